// Round 10
// baseline (880.463 us; speedup 1.0000x reference)
//
#include <hip/hip_runtime.h>
#include <hip/hip_bf16.h>
#include <cstdint>
#include <cstddef>

#define N_NODES 50000
#define N_EDGES 600000
#define DF 128
#define N_ETYPES 4
#define N_STEPS 5
#define SCAN4_NB 782       // ceil(200000/256)
#define GRU_TILES 3125     // 50000/16 exact
#define GRU_BLOCKS 256     // 1 block/CU
#define LSTRIDE 130        // k_gru X row stride (floats): 2-way bank alias only (free)
#define HSTRIDE 136        // k_gru H tile row stride (f16)
#define FS_ROW 140         // k_fused2 S row stride (f16)

typedef _Float16 f16x8 __attribute__((ext_vector_type(8)));
typedef _Float16 f16x4 __attribute__((ext_vector_type(4)));
typedef float f32x4 __attribute__((ext_vector_type(4)));

__device__ __forceinline__ float sigmoid_fast(float x) {
    return 1.0f / (1.0f + __expf(-x));
}
__device__ __forceinline__ float tanh_fast(float x) {
    return 1.0f - 2.0f / (__expf(2.0f * x) + 1.0f);
}

// ---------------- setup kernels (once per launch) ----------------

// Wl -> f16; build concatenated GRU B matrix Bc[g*128+c][k]: k<128 -> wih, else whh
__global__ __launch_bounds__(256) void k_cvt_w(
    const float* __restrict__ Wl, const float* __restrict__ wih,
    const float* __restrict__ whh, _Float16* __restrict__ Wl_h,
    _Float16* __restrict__ Bc) {
    int i = blockIdx.x * 256 + threadIdx.x;          // grid covers 98304
    if (i < N_ETYPES * DF * DF) Wl_h[i] = (_Float16)Wl[i];
    int row = i >> 8;                                // 0..383 = g*128 + c
    int k = i & 255;
    float v = (k < 128) ? wih[row * 128 + k] : whh[row * 128 + (k - 128)];
    Bc[i] = (_Float16)v;
}

__global__ __launch_bounds__(256) void k_cvt_h(
    const float* __restrict__ h, _Float16* __restrict__ hh, int n4) {
    int i = blockIdx.x * 256 + threadIdx.x;
    if (i < n4) {
        float4 v = ((const float4*)h)[i];
        f16x4 o;
        o.x = (_Float16)v.x; o.y = (_Float16)v.y;
        o.z = (_Float16)v.z; o.w = (_Float16)v.w;
        ((f16x4*)hh)[i] = o;
    }
}

// histogram over (dst, type): deg4[dst*4 + et]
__global__ __launch_bounds__(256) void k_hist4(
    const int* __restrict__ dst, const int* __restrict__ ety,
    int* __restrict__ deg4, int E) {
    int i = blockIdx.x * 256 + threadIdx.x;
    if (i < E) atomicAdd(&deg4[dst[i] * 4 + (ety[i] - 1)], 1);
}

// hierarchical exclusive scan over deg4[0..4N)
__global__ __launch_bounds__(256) void k_part4(
    const int* __restrict__ deg4, int* __restrict__ part, int M) {
    __shared__ int s[256];
    int t = threadIdx.x, i = blockIdx.x * 256 + t;
    s[t] = (i < M) ? deg4[i] : 0;
    __syncthreads();
    for (int off = 128; off > 0; off >>= 1) {
        if (t < off) s[t] += s[t + off];
        __syncthreads();
    }
    if (t == 0) part[blockIdx.x] = s[0];
}

__global__ __launch_bounds__(1024) void k_scan1k(int* __restrict__ part, int nb) {
    __shared__ int s[1024];
    int t = threadIdx.x;
    int v = (t < nb) ? part[t] : 0;
    s[t] = v;
    __syncthreads();
    for (int off = 1; off < 1024; off <<= 1) {
        int u = (t >= off) ? s[t - off] : 0;
        __syncthreads();
        s[t] += u;
        __syncthreads();
    }
    if (t < nb) part[t] = s[t] - v;                  // exclusive prefix of block sums
}

__global__ __launch_bounds__(256) void k_row4(
    const int* __restrict__ deg4, const int* __restrict__ part,
    int* __restrict__ row_start4, int* __restrict__ cursor4, int M) {
    __shared__ int s[256];
    int t = threadIdx.x, i = blockIdx.x * 256 + t;
    int d = (i < M) ? deg4[i] : 0;
    s[t] = d;
    __syncthreads();
    for (int off = 1; off < 256; off <<= 1) {
        int u = (t >= off) ? s[t - off] : 0;
        __syncthreads();
        s[t] += u;
        __syncthreads();
    }
    int rs = part[blockIdx.x] + s[t] - d;
    if (i < M) {
        row_start4[i] = rs;
        cursor4[i] = rs;
        if (i == M - 1) row_start4[M] = rs + d;
    }
}

__global__ __launch_bounds__(256) void k_fill4(
    const int* __restrict__ src, const int* __restrict__ dst,
    const int* __restrict__ ety, int* __restrict__ cursor4,
    int* __restrict__ csr, int E) {
    int i = blockIdx.x * 256 + threadIdx.x;
    if (i < E) {
        int slot = atomicAdd(&cursor4[dst[i] * 4 + (ety[i] - 1)], 1);
        csr[slot] = src[i];                          // type implied by segment
    }
}

// ---------------- per-step kernels ----------------

// Fused transform+aggregate, type-sorted CSR (NO per-edge type masking):
//   a[n] = sum_t W_t * (sum_{seg(n,t)} h[src]) + sum_t len(seg(n,t)) * b_t
// One block per 16-node tile.
// Phase 1: per-type gather-sums of h into LDS S (frag-major, f16); counts free.
// Phase 2: 4x K=128 MFMA GEMM vs L2-resident f16 weights (verified in R8).
__global__ __launch_bounds__(256, 4) void k_fused2(
    const _Float16* __restrict__ hh, const _Float16* __restrict__ Wl,
    const float* __restrict__ b_lin, const int* __restrict__ row_start4,
    const int* __restrict__ csr, _Float16* __restrict__ ah) {
    __shared__ _Float16 S[64 * FS_ROW];              // [(t*4+kt)*4+q][node*8+j]
    __shared__ float CNT[16][4];
    const int wave = threadIdx.x >> 6, lane = threadIdx.x & 63;
    const int g4 = lane >> 4, c8 = lane & 15;
    const int tile = blockIdx.x;

    // ---- phase 1: wave w owns nodes w*4..w*4+3 of the tile.
#pragma unroll
    for (int v = 0; v < 4; v++) {
        const int nd = wave * 4 + v;
        const int n = tile * 16 + nd;
        const int b0 = row_start4[4 * n + 0];
        const int b1 = row_start4[4 * n + 1];
        const int b2 = row_start4[4 * n + 2];
        const int b3 = row_start4[4 * n + 3];
        const int b4 = row_start4[4 * n + 4];
        const int tb[5] = {b0, b1, b2, b3, b4};
#pragma unroll
        for (int t = 0; t < 4; t++) {
            const int sb = tb[t], se = tb[t + 1];
            float acc[8] = {0.f, 0.f, 0.f, 0.f, 0.f, 0.f, 0.f, 0.f};
            for (int e = sb; e < se; e += 8) {
                int i0 = e + g4, i1 = e + 4 + g4;
                float m0 = (i0 < se) ? 1.f : 0.f;
                float m1 = (i1 < se) ? 1.f : 0.f;
                int j0 = (i0 < se) ? i0 : sb;
                int j1 = (i1 < se) ? i1 : sb;
                int s0 = csr[j0], s1 = csr[j1];
                const f16x8 x0 = *(const f16x8*)(hh + (((size_t)s0) << 7) + c8 * 8);
                const f16x8 x1 = *(const f16x8*)(hh + (((size_t)s1) << 7) + c8 * 8);
#pragma unroll
                for (int j = 0; j < 8; j++)
                    acc[j] += m0 * (float)x0[j] + m1 * (float)x1[j];
            }
#pragma unroll
            for (int j = 0; j < 8; j++) {
                acc[j] += __shfl_xor(acc[j], 32, 64);
                acc[j] += __shfl_xor(acc[j], 16, 64);
            }
            if (lane < 16) {
                const int kt = c8 >> 2, q = c8 & 3;
                f16x8 o;
#pragma unroll
                for (int j = 0; j < 8; j++) o[j] = (_Float16)acc[j];
                *(f16x8*)&S[((t * 4 + kt) * 4 + q) * FS_ROW + nd * 8] = o;
            }
            if (lane == 0) CNT[nd][t] = (float)(se - sb);
        }
    }
    __syncthreads();

    // ---- phase 2: a_tile = sum_t S_t @ W_t^T + cnt*b. Wave w -> ft {2w, 2w+1}.
    const int m = lane & 15, q = lane >> 4;
    f16x8 A[4][4];
#pragma unroll
    for (int t = 0; t < 4; t++)
#pragma unroll
        for (int kt = 0; kt < 4; kt++)
            A[t][kt] = *(const f16x8*)&S[((t * 4 + kt) * 4 + q) * FS_ROW + m * 8];
#pragma unroll
    for (int f = 0; f < 2; f++) {
        const int ft = wave * 2 + f;
        f32x4 a = {0.f, 0.f, 0.f, 0.f};
#pragma unroll
        for (int t = 0; t < 4; t++) {
            const _Float16* wrow = Wl + (size_t)t * DF * DF + (size_t)(ft * 16 + m) * DF + q * 8;
#pragma unroll
            for (int kt = 0; kt < 4; kt++)
                a = __builtin_amdgcn_mfma_f32_16x16x32_f16(
                    A[t][kt], *(const f16x8*)(wrow + kt * 32), a, 0, 0, 0);
        }
        const int c = ft * 16 + m;
        const float bl0 = b_lin[c], bl1 = b_lin[128 + c];
        const float bl2 = b_lin[256 + c], bl3 = b_lin[384 + c];
#pragma unroll
        for (int i = 0; i < 4; i++) {
            const int row = q * 4 + i;
            float bias = CNT[row][0] * bl0 + CNT[row][1] * bl1 +
                         CNT[row][2] * bl2 + CNT[row][3] * bl3;
            ah[(((size_t)(tile * 16 + row)) << 7) + c] = (_Float16)(a[i] + bias);
        }
    }
}

// GRU, gate-parallel. vs R9: prefetch REMOVED (proven useless; frees 32 VGPRs
// so the pinned B frags can stay resident), biases hoisted out of the tile loop
// (col = tid&127 is loop-invariant; kills ~150K global loads/block).
__global__ __launch_bounds__(768, 3) void k_gru(
    const _Float16* __restrict__ ah, const _Float16* __restrict__ hh,
    const _Float16* __restrict__ Bc, const float* __restrict__ b_ih,
    const float* __restrict__ b_hh, _Float16* __restrict__ hh_next,
    float* __restrict__ out_f32) {
    __shared__ float X[4 * 16 * LSTRIDE];            // gate exchange, 33 KB
    __shared__ _Float16 H[16 * HSTRIDE];             // hprev tile, 4.25 KB
    const int wave = threadIdx.x >> 6, lane = threadIdx.x & 63;
    const int col16 = lane & 15, quad = lane >> 4;
    const int g = wave >> 2;                         // gate 0..2
    const int s = wave & 3;                          // col-slice of 32

    f16x8 b[2][8];
#pragma unroll
    for (int ct = 0; ct < 2; ct++) {
        const _Float16* bp = Bc + (((size_t)(g * 128 + s * 32 + ct * 16 + col16)) << 8) + quad * 8;
#pragma unroll
        for (int kt = 0; kt < 8; kt++) b[ct][kt] = *(const f16x8*)(bp + kt * 32);
    }
#pragma unroll
    for (int ct = 0; ct < 2; ct++)
#pragma unroll
        for (int kt = 0; kt < 8; kt++)
            asm volatile("" : "+v"(b[ct][kt]));      // pin: no remat-from-global

    // hoisted epilogue biases (col fixed per thread: 768 % 128 == 0)
    const int ecol = threadIdx.x & 127;
    const float bR  = b_ih[ecol] + b_hh[ecol];
    const float bZ  = b_ih[128 + ecol] + b_hh[128 + ecol];
    const float bIN = b_ih[256 + ecol];
    const float bHN = b_hh[256 + ecol];

    for (int tile = blockIdx.x; tile < GRU_TILES; tile += GRU_BLOCKS) {
        const int r0 = tile * 16;
        const int arow = r0 + col16;
        f16x8 A[8];                                  // kt<4 = a, kt>=4 = h
        const _Float16* ap = ah + ((size_t)arow << 7) + quad * 8;
        const _Float16* hp = hh + ((size_t)arow << 7) + quad * 8;
#pragma unroll
        for (int kt = 0; kt < 4; kt++) A[kt] = *(const f16x8*)(ap + kt * 32);
#pragma unroll
        for (int kt = 0; kt < 4; kt++) A[4 + kt] = *(const f16x8*)(hp + kt * 32);

        f32x4 acc[2][2];                             // [khalf-set][ct]; g<2 uses set 0
#pragma unroll
        for (int u = 0; u < 2; u++)
#pragma unroll
            for (int ct = 0; ct < 2; ct++) acc[u][ct] = (f32x4){0.f, 0.f, 0.f, 0.f};
#pragma unroll
        for (int kt = 0; kt < 8; kt++) {
            const int set = (g == 2 && kt >= 4) ? 1 : 0;
#pragma unroll
            for (int ct = 0; ct < 2; ct++)
                acc[set][ct] = __builtin_amdgcn_mfma_f32_16x16x32_f16(
                    A[kt], b[ct][kt], acc[set][ct], 0, 0, 0);
        }

        // wave 0 exports its h-half A frags -> H (epilogue's hprev source)
        if (wave == 0) {
#pragma unroll
            for (int kt = 0; kt < 4; kt++)
                *(f16x8*)&H[col16 * HSTRIDE + kt * 32 + quad * 8] = A[4 + kt];
        }

        // acc -> X exchange
#pragma unroll
        for (int ct = 0; ct < 2; ct++) {
            const int cbase = s * 32 + ct * 16 + col16;
            if (g < 2) {
#pragma unroll
                for (int i = 0; i < 4; i++)
                    X[g * (16 * LSTRIDE) + (quad * 4 + i) * LSTRIDE + cbase] = acc[0][ct][i];
            } else {
#pragma unroll
                for (int i = 0; i < 4; i++) {
                    X[2 * (16 * LSTRIDE) + (quad * 4 + i) * LSTRIDE + cbase] = acc[0][ct][i];
                    X[3 * (16 * LSTRIDE) + (quad * 4 + i) * LSTRIDE + cbase] = acc[1][ct][i];
                }
            }
        }
        // barrier 1: drain LDS writes only
        asm volatile("s_waitcnt lgkmcnt(0)\n\ts_barrier" ::: "memory");

        // epilogue: 2048 elems over 768 threads; no global loads
#pragma unroll
        for (int pazz = 0; pazz < 3; pazz++) {
            int e = threadIdx.x + pazz * 768;
            if (e < 2048) {
                int row = e >> 7;
                float vr = X[0 * (16 * LSTRIDE) + row * LSTRIDE + ecol];
                float vz = X[1 * (16 * LSTRIDE) + row * LSTRIDE + ecol];
                float vin = X[2 * (16 * LSTRIDE) + row * LSTRIDE + ecol];
                float vhn = X[3 * (16 * LSTRIDE) + row * LSTRIDE + ecol];
                float r = sigmoid_fast(vr + bR);
                float z = sigmoid_fast(vz + bZ);
                float nn = tanh_fast(vin + bIN + r * (vhn + bHN));
                float hprev = (float)H[row * HSTRIDE + ecol];
                size_t idx = ((size_t)(r0 + row) << 7) + ecol;
                float hv = (1.f - z) * nn + z * hprev;
                hh_next[idx] = (_Float16)hv;
                if (out_f32) out_f32[idx] = hv;
            }
        }
        // barrier 2: epilogue LDS reads already consumed
        asm volatile("s_barrier" ::: "memory");
    }
}

// ---------------- launch ----------------

extern "C" void kernel_launch(void* const* d_in, const int* in_sizes, int n_in,
                              void* d_out, int out_size, void* d_ws, size_t ws_size,
                              hipStream_t stream) {
    const float* h0    = (const float*)d_in[0];
    const int*   src   = (const int*)d_in[1];
    const int*   dst   = (const int*)d_in[2];
    const int*   ety   = (const int*)d_in[3];
    const float* W_lin = (const float*)d_in[4];
    const float* b_lin = (const float*)d_in[5];
    const float* w_ih  = (const float*)d_in[6];
    const float* w_hh  = (const float*)d_in[7];
    const float* b_ih  = (const float*)d_in[8];
    const float* b_hh  = (const float*)d_in[9];
    float* hout = (float*)d_out;

    char* p = (char*)d_ws;
    auto alloc = [&](size_t bytes) -> char* {
        char* r = p;
        p += (bytes + 255) & ~(size_t)255;
        return r;
    };
    _Float16* h_a    = (_Float16*)alloc((size_t)N_NODES * DF * 2);
    _Float16* h_b    = (_Float16*)alloc((size_t)N_NODES * DF * 2);
    _Float16* a_half = (_Float16*)alloc((size_t)N_NODES * DF * 2);
    _Float16* Wl_h   = (_Float16*)alloc((size_t)N_ETYPES * DF * DF * 2);
    _Float16* Bc     = (_Float16*)alloc((size_t)3 * DF * 2 * DF * 2);   // [384][256] f16
    int* deg4       = (int*)alloc((size_t)4 * N_NODES * 4);
    int* row_start4 = (int*)alloc((size_t)(4 * N_NODES + 1) * 4);
    int* cursor4    = (int*)alloc((size_t)4 * N_NODES * 4);
    int* csr        = (int*)alloc((size_t)N_EDGES * 4);
    int* part       = (int*)alloc((size_t)SCAN4_NB * 4);

    const int M = 4 * N_NODES;                       // 200000
    hipMemsetAsync(deg4, 0, (size_t)M * 4, stream);
    k_cvt_w<<<384, 256, 0, stream>>>(W_lin, w_ih, w_hh, Wl_h, Bc);
    k_cvt_h<<<(N_NODES * DF / 4 + 255) / 256, 256, 0, stream>>>(h0, h_a, N_NODES * DF / 4);
    k_hist4<<<(N_EDGES + 255) / 256, 256, 0, stream>>>(dst, ety, deg4, N_EDGES);
    k_part4<<<SCAN4_NB, 256, 0, stream>>>(deg4, part, M);
    k_scan1k<<<1, 1024, 0, stream>>>(part, SCAN4_NB);
    k_row4<<<SCAN4_NB, 256, 0, stream>>>(deg4, part, row_start4, cursor4, M);
    k_fill4<<<(N_EDGES + 255) / 256, 256, 0, stream>>>(src, dst, ety, cursor4, csr, N_EDGES);

    _Float16* hc = h_a;
    _Float16* hn = h_b;
    for (int s = 0; s < N_STEPS; s++) {
        k_fused2<<<GRU_TILES, 256, 0, stream>>>(hc, Wl_h, b_lin, row_start4, csr, a_half);
        float* of = (s == N_STEPS - 1) ? hout : nullptr;
        k_gru<<<GRU_BLOCKS, 768, 0, stream>>>(a_half, hc, Bc, b_ih, b_hh, hn, of);
        _Float16* tmp = hc; hc = hn; hn = tmp;
    }
}